// Round 5
// baseline (268.981 us; speedup 1.0000x reference)
//
#include <hip/hip_runtime.h>
#include <hip/hip_bf16.h>
#include <math.h>

// Problem constants (from reference)
#define BATCH 4
#define N_ANCHORS 211200
#define CHANNELS 256
#define FM_H 200
#define FM_W 176
#define NKP 4096
#define PLANE (FM_H * FM_W)                   // 35200 floats

#define BOXES_ELEMS (BATCH * N_ANCHORS * 7)   // 5,913,600
#define BEV_ELEMS   (BATCH * CHANNELS * NKP)  // 4,194,304

// Native clang vector type (__builtin_nontemporal_store rejects HIP float4).
typedef float floatx4 __attribute__((ext_vector_type(4)));

// Split-plane parameters for the gather path.
// half0: stages rows [0, 104), owns keypoints with y0 in [0, 102]  (y1 <= 103)
// half1: stages rows [103, 200), owns keypoints with y0 in [103, 200]
#define H_SPLIT   103
#define ROWS_H0   104                          // 104*176*4 = 73216 B
#define ROWS_H1   97                           // 97*176*4  = 68288 B
#define GATHER_LDS_BYTES (ROWS_H0 * FM_W * 4)  // 73216 B -> 2 blocks/CU

#define G_GATHER (BATCH * CHANNELS * 2)        // 2048 gather blocks
#define G_DECODE 1024                          // decode blocks (grid-stride)
#define NTHREADS 1024

// ---------------------------------------------------------------------------
// ONE fused kernel, block-specialized:
//   blocks [0, 2048): BEV bilinear gather, split plane-in-LDS (R4-verified).
//   blocks [2048, 3072): box decode, branchless elementwise (r = j mod 7).
// Rationale: (a) decode's pure streaming overlaps gather's LDS-compute
// phases instead of serializing behind them; (b) the single dispatch is
// large enough to surface in rocprof top-5 with counters (the two separate
// kernels were hidden below the 83 us harness fills).
// ---------------------------------------------------------------------------
__global__ __launch_bounds__(1024) void pvrcnn_fused_kernel(
    const float* __restrict__ deltas,      // [B, N_ANCHORS, 7]
    const float* __restrict__ anchors,     // [B, N_ANCHORS, 7]
    const float* __restrict__ fm,          // [B, C, H, W]
    const float* __restrict__ kp,          // [B, K, 3]
    float* __restrict__ out_boxes,         // [B, N_ANCHORS, 7]
    float* __restrict__ out_bev)           // [B, C, K]
{
    const int tid = threadIdx.x;

    if (blockIdx.x >= G_GATHER) {
        // ---------------- decode path (no LDS, no barriers) ----------------
        // Element j: r = j%7 selects the formula. Per-box anchor extras
        // (a3,a4,a5) are wave-broadcast / L1 hits (same lines as the
        // coalesced anchors[j] stream) -> no extra HBM traffic.
        //   r in {0,1}: d*||a_wl|| + a[j]
        //   r == 2    : d*a_h + a[j]
        //   r in {3..5}: exp(d)*a[j]
        //   r == 6    : d + a[j]
        const int db = blockIdx.x - G_GATHER;
        const int stride = G_DECODE * NTHREADS;
        for (int j = db * NTHREADS + tid; j < BOXES_ELEMS; j += stride) {
            int box  = j / 7;
            int r    = j - box * 7;
            int base = box * 7;
            float d  = deltas[j];
            float aj = anchors[j];
            float a3 = anchors[base + 3];
            float a4 = anchors[base + 4];
            float a5 = anchors[base + 5];
            float dn = sqrtf(a3 * a3 + a4 * a4);
            float ex = expf(d);
            float s  = (r < 2) ? dn : a5;        // r<=2 multiplier for d
            float o  = (r <= 2) ? (d * s + aj)
                     : (r <= 5) ? (ex * aj)
                                : (d + aj);
            __builtin_nontemporal_store(o, out_boxes + j);
        }
        return;
    }

    // ---------------- gather path (split plane-in-LDS, R4-verified) --------
    extern __shared__ float tile[];        // up to ROWS_H0 * FM_W floats

    const int blk  = blockIdx.x;
    const int half = blk & 1;
    const int bc   = blk >> 1;             // b*CHANNELS + c
    const int b    = bc >> 8;              // CHANNELS == 256

    const int row_lo = half ? H_SPLIT : 0;
    const int rows   = half ? ROWS_H1 : ROWS_H0;

    // Stage rows [row_lo, row_lo+rows) of plane bc into LDS; 44 float4/row.
    const floatx4* gp = (const floatx4*)(fm + (size_t)bc * PLANE + row_lo * FM_W);
    floatx4* lp = (floatx4*)tile;
    const int n4 = rows * (FM_W / 4);
    for (int i = tid; i < n4; i += NTHREADS) lp[i] = gp[i];
    __syncthreads();

    const float* kpb  = kp + (size_t)b * NKP * 3;
    float*       outp = out_bev + (size_t)bc * NKP;

#pragma unroll
    for (int m = 0; m < NKP / NTHREADS; ++m) {
        int k = tid + m * NTHREADS;
        float kx = kpb[k * 3 + 0];
        float ky = kpb[k * 3 + 1];

        // indices = (xy - pixel_offset) / (voxel_size * stride); voxel=0.05, stride=8
        float ix_idx = kx / 0.4f;
        float iy_idx = (ky + 40.0f) / 0.4f;
        ix_idx = fminf(fmaxf(ix_idx, 0.0f), (float)(FM_W - 1));
        iy_idx = fminf(fmaxf(iy_idx, 0.0f), (float)(FM_H - 1));
        float nx = 2.0f * (ix_idx / (float)(FM_W - 2)) - 1.0f;
        float ny = 2.0f * (iy_idx / (float)(FM_H - 2)) - 1.0f;
        // grid flip: width coord gets ny, height coord gets nx
        float ix = (ny + 1.0f) * 0.5f * (float)(FM_W - 1);
        float iy = (nx + 1.0f) * 0.5f * (float)(FM_H - 1);

        float x0f = floorf(ix);
        float y0f = floorf(iy);
        float wx = ix - x0f;
        float wy = iy - y0f;
        int x0 = (int)x0f, y0 = (int)y0f;   // y0 in [0, 200], x0 in [0, 175]
        int x1 = x0 + 1,   y1 = y0 + 1;

        bool mine = half ? (y0 >= H_SPLIT) : (y0 < H_SPLIT);

        float vx1 = (x1 <= FM_W - 1) ? 1.0f : 0.0f;     // x0 always valid
        float vy0 = (y0 <= FM_H - 1) ? 1.0f : 0.0f;     // y0 can be 200
        float vy1 = (y1 <= FM_H - 1) ? 1.0f : 0.0f;

        int xc1 = min(x1, FM_W - 1);
        int yc0 = min(y0, FM_H - 1) - row_lo;           // LDS row index
        int yc1 = min(y1, FM_H - 1) - row_lo;
        // Clamp LDS rows into the staged window (only matters for !mine
        // lanes, whose result is discarded; keeps ds_read in-bounds).
        yc0 = min(max(yc0, 0), rows - 1);
        yc1 = min(max(yc1, 0), rows - 1);

        float v00 = tile[yc0 * FM_W + x0 ] * vy0;
        float v01 = tile[yc0 * FM_W + xc1] * (vx1 * vy0);
        float v10 = tile[yc1 * FM_W + x0 ] * vy1;
        float v11 = tile[yc1 * FM_W + xc1] * (vx1 * vy1);

        float r = v00 * (1.0f - wx) * (1.0f - wy)
                + v01 * wx * (1.0f - wy)
                + v10 * (1.0f - wx) * wy
                + v11 * wx * wy;

        if (mine) __builtin_nontemporal_store(r, outp + k);
    }
}

extern "C" void kernel_launch(void* const* d_in, const int* in_sizes, int n_in,
                              void* d_out, int out_size, void* d_ws, size_t ws_size,
                              hipStream_t stream)
{
    const float* deltas  = (const float*)d_in[0];
    const float* anchors = (const float*)d_in[1];
    const float* fm      = (const float*)d_in[2];
    const float* kp      = (const float*)d_in[3];

    float* out_boxes = (float*)d_out;
    float* out_bev   = (float*)d_out + BOXES_ELEMS;

    // Allow >64KB dynamic LDS (host-side, idempotent, graph-capture safe).
    static bool attr_set = false;
    if (!attr_set) {
        (void)hipFuncSetAttribute((const void*)pvrcnn_fused_kernel,
                                  hipFuncAttributeMaxDynamicSharedMemorySize,
                                  GATHER_LDS_BYTES);
        attr_set = true;
    }

    const int blocks = G_GATHER + G_DECODE;   // 3072
    pvrcnn_fused_kernel<<<blocks, NTHREADS, GATHER_LDS_BYTES, stream>>>(
        deltas, anchors, fm, kp, out_boxes, out_bev);
}